// Round 1
// baseline (259.651 us; speedup 1.0000x reference)
//
#include <hip/hip_runtime.h>
#include <stdint.h>

// WildCatPool: per (b,c) row of n=112*112=12544 fp32 values, mean of top
// kmax = 6272 values. 6400 rows total. One block per row; row staged in LDS;
// 4-level radix select (8 bits/level) on monotone uint keys; final sum pass.

constexpr int N_ELEM = 112 * 112;   // 12544
constexpr int KMAX   = 6272;        // round(0.5 * 12544)
constexpr int NT     = 256;         // threads per block (4 waves)
constexpr int NVEC   = N_ELEM / 4;  // 3136 16B chunks

// order-preserving float -> uint key (larger float => larger key)
__device__ __forceinline__ unsigned int f2key(float f) {
    unsigned int u = __float_as_uint(f);
    return u ^ ((unsigned int)(((int)u) >> 31) | 0x80000000u);
}

__global__ __launch_bounds__(NT, 3)
void wildcat_topk_kernel(const float* __restrict__ x, float* __restrict__ out) {
    __shared__ __align__(16) float buf[N_ELEM];   // 50176 B
    __shared__ unsigned int hist[256];
    __shared__ unsigned int s_sel[2];             // [0]=selected bin, [1]=count strictly above
    __shared__ float s_part[4];

    const int row = blockIdx.x;
    const int t   = threadIdx.x;
    const float* src = x + (size_t)row * N_ELEM;

    // ---- stage row: global -> LDS, 16 B per lane, async direct-to-LDS ----
    for (int i = t; i < NVEC; i += NT) {
        __builtin_amdgcn_global_load_lds(
            (const __attribute__((address_space(1))) float*)(src + 4 * i),
            (__attribute__((address_space(3))) float*)(&buf[4 * i]),
            16, 0, 0);
    }
    __syncthreads();  // drains vmcnt before barrier

    unsigned int prefix = 0;   // selected high bits of threshold key
    unsigned int krem   = KMAX;

    // ---- 4-level radix select, 8 bits per level ----
    for (int level = 0; level < 4; ++level) {
        const int shift = 24 - 8 * level;
        hist[t] = 0;   // 256 threads, 256 bins
        __syncthreads();
        const unsigned int pmask = level ? (0xFFFFFFFFu << (shift + 8)) : 0u;
        for (int i = t; i < N_ELEM; i += NT) {
            unsigned int key = f2key(buf[i]);
            if ((key & pmask) == prefix) {
                atomicAdd(&hist[(key >> shift) & 255u], 1u);
            }
        }
        __syncthreads();

        // wave 0: suffix-scan from top bin, find bin containing the krem-th largest
        if (t < 64) {
            unsigned int h0 = hist[4 * t + 0], h1 = hist[4 * t + 1];
            unsigned int h2 = hist[4 * t + 2], h3 = hist[4 * t + 3];
            unsigned int local = h0 + h1 + h2 + h3;
            unsigned int suf = local;           // will become sum over lanes >= t
            #pragma unroll
            for (int d = 1; d < 64; d <<= 1) {
                unsigned int v = __shfl_down(suf, d);
                if (t + d < 64) suf += v;
            }
            unsigned int above = suf - local;   // sum of bins >= 4*(t+1)
            if (above < krem && krem <= suf) {  // unique crossing lane
                unsigned int c = above; int sel; unsigned int cab;
                if      (c + h3 >= krem)           { sel = 4 * t + 3; cab = c; }
                else if (c + h3 + h2 >= krem)      { sel = 4 * t + 2; cab = c + h3; }
                else if (c + h3 + h2 + h1 >= krem) { sel = 4 * t + 1; cab = c + h3 + h2; }
                else                               { sel = 4 * t + 0; cab = c + h3 + h2 + h1; }
                s_sel[0] = (unsigned int)sel;
                s_sel[1] = cab;
            }
        }
        __syncthreads();
        prefix |= s_sel[0] << shift;
        krem   -= s_sel[1];   // elements still needed from the selected bin
    }

    // prefix == exact threshold key T; krem == # of elements equal to T to include
    // ---- final pass: sum of values with key > T ----
    float sum = 0.f;
    for (int i = t; i < N_ELEM; i += NT) {
        float f = buf[i];
        if (f2key(f) > prefix) sum += f;
    }
    #pragma unroll
    for (int d = 1; d < 64; d <<= 1) sum += __shfl_xor(sum, d);
    if ((t & 63) == 0) s_part[t >> 6] = sum;
    __syncthreads();

    if (t == 0) {
        float total = s_part[0] + s_part[1] + s_part[2] + s_part[3];
        float valT = (prefix & 0x80000000u) ? __uint_as_float(prefix ^ 0x80000000u)
                                            : __uint_as_float(~prefix);
        out[row] = (total + (float)krem * valT) / (float)KMAX;
    }
}

extern "C" void kernel_launch(void* const* d_in, const int* in_sizes, int n_in,
                              void* d_out, int out_size, void* d_ws, size_t ws_size,
                              hipStream_t stream) {
    const float* x = (const float*)d_in[0];
    float* out = (float*)d_out;
    const int rows = out_size;  // 32*200 = 6400
    wildcat_topk_kernel<<<rows, NT, 0, stream>>>(x, out);
}

// Round 2
// 139.695 us; speedup vs baseline: 1.8587x; 1.8587x over previous
//
#include <hip/hip_runtime.h>
#include <stdint.h>

// WildCatPool: per (b,c) row of n=112*112=12544 fp32, mean of top kmax=6272.
// 6400 rows, one block (256 thr) per row. Row held as 49 monotone uint keys
// per thread IN REGISTERS. 4-level radix select (8 bits/level) with per-wave
// replicated LDS count histograms; final top-k sum is a register pass.

constexpr int N_ELEM = 112 * 112;   // 12544 = 256 * 49
constexpr int KMAX   = 6272;
constexpr int NT     = 256;         // 4 waves
constexpr int PER    = 49;          // elements per thread
constexpr int NW     = 4;           // waves per block
constexpr int HPITCH = 260;         // 256 bins + 4 pad words -> copies 4 banks apart

// order-preserving float -> uint key (larger float => larger key)
__device__ __forceinline__ unsigned int f2key(float f) {
    unsigned int u = __float_as_uint(f);
    return u ^ ((unsigned int)(((int)u) >> 31) | 0x80000000u);
}
__device__ __forceinline__ float key2f(unsigned int k) {
    unsigned int u = (k & 0x80000000u) ? (k ^ 0x80000000u) : ~k;
    return __uint_as_float(u);
}

__global__ __launch_bounds__(NT, 4)
void wildcat_topk_kernel(const float* __restrict__ x, float* __restrict__ out) {
    __shared__ unsigned int hist[NW * HPITCH];  // 4160 B
    __shared__ unsigned int s_sel[2];           // [0]=selected bin, [1]=count strictly above
    __shared__ float s_part[NW];

    const int row = blockIdx.x;
    const int t   = threadIdx.x;
    const float* src = x + (size_t)row * N_ELEM;

    // ---- load row into registers as monotone keys (coalesced float4) ----
    unsigned int key[PER];
    const float4* src4 = (const float4*)src;
    #pragma unroll
    for (int j = 0; j < 12; ++j) {
        float4 v = src4[t + NT * j];
        key[4 * j + 0] = f2key(v.x);
        key[4 * j + 1] = f2key(v.y);
        key[4 * j + 2] = f2key(v.z);
        key[4 * j + 3] = f2key(v.w);
    }
    key[48] = f2key(src[12288 + t]);   // tail: one scalar per thread

    unsigned int* myh = &hist[(t >> 6) * HPITCH];

    unsigned int prefix = 0;
    unsigned int krem   = KMAX;

    // ---- 4-level radix select, 8 bits per level, counts only ----
    for (int level = 0; level < 4; ++level) {
        const int shift = 24 - 8 * level;
        for (int i = t; i < NW * HPITCH; i += NT) hist[i] = 0;
        __syncthreads();

        const unsigned int pmask = level ? (0xFFFFFFFFu << (shift + 8)) : 0u;
        #pragma unroll
        for (int j = 0; j < PER; ++j) {
            unsigned int k = key[j];
            if ((k & pmask) == prefix) {
                atomicAdd(&myh[(k >> shift) & 255u], 1u);
            }
        }
        __syncthreads();

        // wave 0: combine 4 copies, suffix-scan from top, pick crossing bin
        if (t < 64) {
            unsigned int b0 = 0, b1 = 0, b2 = 0, b3 = 0;
            #pragma unroll
            for (int w = 0; w < NW; ++w) {
                b0 += hist[w * HPITCH + 4 * t + 0];
                b1 += hist[w * HPITCH + 4 * t + 1];
                b2 += hist[w * HPITCH + 4 * t + 2];
                b3 += hist[w * HPITCH + 4 * t + 3];
            }
            unsigned int local = b0 + b1 + b2 + b3;
            unsigned int suf = local;
            #pragma unroll
            for (int d = 1; d < 64; d <<= 1) {
                unsigned int v = __shfl_down(suf, d);
                if (t + d < 64) suf += v;
            }
            unsigned int above = suf - local;   // count in bins >= 4*(t+1)
            if (above < krem && krem <= suf) {  // unique crossing lane
                unsigned int c = above; int sel; unsigned int cab;
                if      (c + b3 >= krem)           { sel = 4 * t + 3; cab = c; }
                else if (c + b3 + b2 >= krem)      { sel = 4 * t + 2; cab = c + b3; }
                else if (c + b3 + b2 + b1 >= krem) { sel = 4 * t + 1; cab = c + b3 + b2; }
                else                               { sel = 4 * t + 0; cab = c + b3 + b2 + b1; }
                s_sel[0] = (unsigned int)sel;
                s_sel[1] = cab;
            }
        }
        __syncthreads();
        prefix |= s_sel[0] << shift;
        krem   -= s_sel[1];
    }

    // prefix == exact threshold key T; krem == # elements equal to T to include
    // ---- final register pass: sum of values with key > T ----
    float sum = 0.f;
    #pragma unroll
    for (int j = 0; j < PER; ++j) {
        unsigned int k = key[j];
        if (k > prefix) sum += key2f(k);
    }
    #pragma unroll
    for (int d = 1; d < 64; d <<= 1) sum += __shfl_xor(sum, d);
    if ((t & 63) == 0) s_part[t >> 6] = sum;
    __syncthreads();

    if (t == 0) {
        float total = s_part[0] + s_part[1] + s_part[2] + s_part[3];
        out[row] = (total + (float)krem * key2f(prefix)) / (float)KMAX;
    }
}

extern "C" void kernel_launch(void* const* d_in, const int* in_sizes, int n_in,
                              void* d_out, int out_size, void* d_ws, size_t ws_size,
                              hipStream_t stream) {
    const float* x = (const float*)d_in[0];
    float* out = (float*)d_out;
    const int rows = out_size;  // 6400
    wildcat_topk_kernel<<<rows, NT, 0, stream>>>(x, out);
}

// Round 3
// 76.351 us; speedup vs baseline: 3.4008x; 1.8297x over previous
//
#include <hip/hip_runtime.h>
#include <stdint.h>

// WildCatPool: per (b,c) row of n=112*112=12544 fp32, mean of top kmax=6272.
// 6400 rows, one block (256 thr) per row. Keys in registers. 3-level radix
// select: 13 bits (8192-bin padded LDS hist) + 10 + 9, with survivor
// compaction after level 0. Final sum is a register pass.

constexpr int N_ELEM = 112 * 112;            // 12544 = 256*49
constexpr int KMAX   = 6272;
constexpr int NT     = 256;                  // 4 waves
constexpr int PER    = 49;
constexpr int NBIN0  = 8192;                 // 13-bit level 0
constexpr int HWORDS = NBIN0 + (NBIN0 >> 5); // 8448 padded words (33 KB)
constexpr int SURV_BASE = 1024 + 32;         // L1 padded size; survivors live above
constexpr int CAP   = HWORDS - SURV_BASE;    // 7392 survivor slots

// order-preserving float -> uint key (larger float => larger key)
__device__ __forceinline__ unsigned int f2key(float f) {
    unsigned int u = __float_as_uint(f);
    return u ^ ((unsigned int)(((int)u) >> 31) | 0x80000000u);
}
__device__ __forceinline__ float key2f(unsigned int k) {
    unsigned int u = (k & 0x80000000u) ? (k ^ 0x80000000u) : ~k;
    return __uint_as_float(u);
}
// padded histogram address: one pad word per 32 bins -> conflict-free scans
__device__ __forceinline__ int hidx(int bin) { return bin + (bin >> 5); }

// Find bin containing the krem-th largest over BPT*256 bins (padded layout).
// Writes s_sel[0]=bin, s_sel[1]=count strictly above that bin. Ends synced.
template<int BPT>
__device__ __forceinline__ void pick_bin(const unsigned int* hist, unsigned int krem,
                                         int t, unsigned int* s_sel,
                                         unsigned int* s_wsum) {
    const int lane = t & 63, w = t >> 6;
    const int base = hidx(BPT * t);          // BPT contiguous padded words
    unsigned int local = 0;
    #pragma unroll
    for (int b = 0; b < BPT; ++b) local += hist[base + b];
    unsigned int suf = local;                // suffix-inclusive within wave
    #pragma unroll
    for (int d = 1; d < 64; d <<= 1) {
        unsigned int v = __shfl_down(suf, d);
        if (lane + d < 64) suf += v;
    }
    if (lane == 0) s_wsum[w] = suf;          // wave total
    __syncthreads();
    unsigned int suf_all = suf;
    #pragma unroll
    for (int ww = 0; ww < 4; ++ww) if (ww > w) suf_all += s_wsum[ww];
    unsigned int above = suf_all - local;    // count in bins owned by threads > t
    if (above < krem && krem <= suf_all) {   // unique crossing thread
        unsigned int c = above;
        #pragma unroll
        for (int b = BPT - 1; b >= 0; --b) {
            unsigned int h = hist[base + b];
            if (c + h >= krem) { s_sel[0] = (unsigned int)(BPT * t + b); s_sel[1] = c; break; }
            c += h;
        }
    }
    __syncthreads();
}

__global__ __launch_bounds__(NT, 4)
void wildcat_topk_kernel(const float* __restrict__ x, float* __restrict__ out) {
    __shared__ unsigned int hist[HWORDS];    // 33 KB; surv list aliased above 1056
    __shared__ unsigned int s_sel[2];
    __shared__ unsigned int s_wsum[4];
    __shared__ unsigned int s_cnt;
    __shared__ float s_part[4];

    const int row = blockIdx.x;
    const int t   = threadIdx.x;
    const float* src = x + (size_t)row * N_ELEM;

    // ---- load row into registers as monotone keys (coalesced float4) ----
    unsigned int key[PER];
    const float4* src4 = (const float4*)src;
    #pragma unroll
    for (int j = 0; j < 12; ++j) {
        float4 v = src4[t + NT * j];
        key[4 * j + 0] = f2key(v.x);
        key[4 * j + 1] = f2key(v.y);
        key[4 * j + 2] = f2key(v.z);
        key[4 * j + 3] = f2key(v.w);
    }
    key[48] = f2key(src[12288 + t]);

    for (int i = t; i < HWORDS; i += NT) hist[i] = 0;
    if (t == 0) s_cnt = 0;
    __syncthreads();

    // ---- level 0: bits [31:19], 8192 bins ----
    #pragma unroll
    for (int j = 0; j < PER; ++j)
        atomicAdd(&hist[hidx(key[j] >> 19)], 1u);
    __syncthreads();

    pick_bin<32>(hist, KMAX, t, s_sel, s_wsum);
    const unsigned int sel0 = s_sel[0];
    unsigned int krem = KMAX - s_sel[1];
    const unsigned int nsel = hist[hidx(sel0)];
    const bool uselist = (nsel <= (unsigned int)CAP);
    __syncthreads();   // all reads of hist/s_sel done before zero/compact writes

    // ---- compact survivors (sel0 bin) while zeroing L1 bins ----
    unsigned int* surv = &hist[SURV_BASE];
    if (uselist) {
        #pragma unroll
        for (int j = 0; j < PER; ++j) {
            if ((key[j] >> 19) == sel0) {
                unsigned int p = atomicAdd(&s_cnt, 1u);
                surv[p] = key[j];
            }
        }
    }
    for (int i = t; i < SURV_BASE; i += NT) hist[i] = 0;
    __syncthreads();
    const int m = (int)s_cnt;

    // ---- level 1: bits [18:9], 1024 bins ----
    if (uselist) {
        for (int i = t; i < m; i += NT) {
            unsigned int e = surv[i];
            atomicAdd(&hist[hidx((e >> 9) & 1023u)], 1u);
        }
    } else {
        #pragma unroll
        for (int j = 0; j < PER; ++j)
            if ((key[j] >> 19) == sel0)
                atomicAdd(&hist[hidx((key[j] >> 9) & 1023u)], 1u);
    }
    __syncthreads();

    pick_bin<4>(hist, krem, t, s_sel, s_wsum);
    const unsigned int sel1 = s_sel[0];
    krem -= s_sel[1];
    const unsigned int p219 = (sel0 << 10) | sel1;   // bits [31:9] of threshold

    // zero L2 bins (512 bins + pads = 528 words); nothing reads them now
    for (int i = t; i < 528; i += NT) hist[i] = 0;
    __syncthreads();

    // ---- level 2: bits [8:0], 512 bins ----
    if (uselist) {
        for (int i = t; i < m; i += NT) {
            unsigned int e = surv[i];
            if (((e >> 9) & 1023u) == sel1)
                atomicAdd(&hist[hidx(e & 511u)], 1u);
        }
    } else {
        #pragma unroll
        for (int j = 0; j < PER; ++j)
            if ((key[j] >> 9) == p219)
                atomicAdd(&hist[hidx(key[j] & 511u)], 1u);
    }
    __syncthreads();

    pick_bin<2>(hist, krem, t, s_sel, s_wsum);
    krem -= s_sel[1];
    const unsigned int prefix = (p219 << 9) | s_sel[0];  // exact threshold key

    // ---- final register pass: sum of values with key > threshold ----
    float sum = 0.f;
    #pragma unroll
    for (int j = 0; j < PER; ++j)
        if (key[j] > prefix) sum += key2f(key[j]);
    #pragma unroll
    for (int d = 1; d < 64; d <<= 1) sum += __shfl_xor(sum, d);
    if ((t & 63) == 0) s_part[t >> 6] = sum;
    __syncthreads();

    if (t == 0) {
        float total = s_part[0] + s_part[1] + s_part[2] + s_part[3];
        out[row] = (total + (float)krem * key2f(prefix)) / (float)KMAX;
    }
}

extern "C" void kernel_launch(void* const* d_in, const int* in_sizes, int n_in,
                              void* d_out, int out_size, void* d_ws, size_t ws_size,
                              hipStream_t stream) {
    const float* x = (const float*)d_in[0];
    float* out = (float*)d_out;
    const int rows = out_size;  // 6400
    wildcat_topk_kernel<<<rows, NT, 0, stream>>>(x, out);
}